// Round 2
// baseline (1046.823 us; speedup 1.0000x reference)
//
#include <hip/hip_runtime.h>
#include <hip/hip_bf16.h>
#include <stdint.h>

#define DEV __device__ __forceinline__

// ---------- bf16 bit helpers (aggregation buffer only) ----------
DEV uint16_t f2bfbits(float f) {          // round-to-nearest-even
    uint32_t x = __float_as_uint(f);
    uint32_t r = x + 0x7fffu + ((x >> 16) & 1u);
    return (uint16_t)(r >> 16);
}

// ---------- overloaded 8-element loaders (contiguous -> fp32[8]) ----------
DEV void ld8(const float* p, float* f) {
    float4 a = *reinterpret_cast<const float4*>(p);
    float4 b = *reinterpret_cast<const float4*>(p + 4);
    f[0] = a.x; f[1] = a.y; f[2] = a.z; f[3] = a.w;
    f[4] = b.x; f[5] = b.y; f[6] = b.z; f[7] = b.w;
}
DEV void ld8(const uint16_t* p, float* f) {
    uint4 v = *reinterpret_cast<const uint4*>(p);
    f[0] = __uint_as_float(v.x << 16); f[1] = __uint_as_float(v.x & 0xffff0000u);
    f[2] = __uint_as_float(v.y << 16); f[3] = __uint_as_float(v.y & 0xffff0000u);
    f[4] = __uint_as_float(v.z << 16); f[5] = __uint_as_float(v.z & 0xffff0000u);
    f[6] = __uint_as_float(v.w << 16); f[7] = __uint_as_float(v.w & 0xffff0000u);
}

// ---------------------- CSR build ----------------------
__global__ void k_count(const int* __restrict__ dst, int e, int* __restrict__ deg) {
    int i = blockIdx.x * 256 + threadIdx.x;
    if (i < e) atomicAdd(&deg[dst[i]], 1);
}

__global__ void k_block_sums(const int* __restrict__ deg, int n, int* __restrict__ bsum) {
    __shared__ int sm[256];
    int base = blockIdx.x * 1024;
    int s = 0;
    for (int i = threadIdx.x; i < 1024; i += 256) {
        int g = base + i;
        if (g < n) s += deg[g];
    }
    sm[threadIdx.x] = s; __syncthreads();
    for (int o = 128; o > 0; o >>= 1) {
        if (threadIdx.x < o) sm[threadIdx.x] += sm[threadIdx.x + o];
        __syncthreads();
    }
    if (threadIdx.x == 0) bsum[blockIdx.x] = sm[0];
}

// exclusive scan of block sums (nb <= 256; here nb = ceil(100000/1024) = 98)
__global__ void k_scan_bsums(int* bsum, int nb) {
    __shared__ int sm[256];
    int t = threadIdx.x;
    int v = (t < nb) ? bsum[t] : 0;
    sm[t] = v; __syncthreads();
    for (int o = 1; o < 256; o <<= 1) {
        int add = (t >= o) ? sm[t - o] : 0;
        __syncthreads();
        sm[t] += add;
        __syncthreads();
    }
    if (t < nb) bsum[t] = (t == 0) ? 0 : sm[t - 1];
}

__global__ void k_scan_final(const int* __restrict__ deg, int n,
                             const int* __restrict__ bsum, int* __restrict__ offs) {
    __shared__ int sm[256];
    int t = threadIdx.x;
    int i0 = blockIdx.x * 1024 + t * 4;
    int d0 = (i0     < n) ? deg[i0]     : 0;
    int d1 = (i0 + 1 < n) ? deg[i0 + 1] : 0;
    int d2 = (i0 + 2 < n) ? deg[i0 + 2] : 0;
    int d3 = (i0 + 3 < n) ? deg[i0 + 3] : 0;
    int ts = d0 + d1 + d2 + d3;
    sm[t] = ts; __syncthreads();
    for (int o = 1; o < 256; o <<= 1) {
        int add = (t >= o) ? sm[t - o] : 0;
        __syncthreads();
        sm[t] += add;
        __syncthreads();
    }
    int e0 = bsum[blockIdx.x] + ((t == 0) ? 0 : sm[t - 1]);
    int e1 = e0 + d0, e2 = e1 + d1, e3 = e2 + d2, e4 = e3 + d3;
    if (i0     < n) offs[i0]     = e0;
    if (i0 + 1 < n) offs[i0 + 1] = e1;
    if (i0 + 2 < n) offs[i0 + 2] = e2;
    if (i0 + 3 < n) offs[i0 + 3] = e3;
    if (i0 <= n - 1 && n - 1 < i0 + 4) offs[n] = e4;  // total
}

__global__ void k_copy_int(const int* __restrict__ a, int* __restrict__ b, int n) {
    int i = blockIdx.x * 256 + threadIdx.x;
    if (i < n) b[i] = a[i];
}

__global__ void k_scatter(const int* __restrict__ src, const int* __restrict__ dst, int e,
                          int* __restrict__ cursor, int* __restrict__ csr) {
    int i = blockIdx.x * 256 + threadIdx.x;
    if (i < e) {
        int p = atomicAdd(&cursor[dst[i]], 1);
        csr[p] = src[i];
    }
}

// ---------------------- aggregation: mean or max over CSR neighbors ----------------------
// fp32 in, bf16 out (GEMM A-operand). one wave per node; lane covers C = D/64 channels.
template<int D, bool MAXAGG>
__global__ __launch_bounds__(256) void k_aggr(const float* __restrict__ X,
                                              const int* __restrict__ offs,
                                              const int* __restrict__ csr,
                                              int n, uint16_t* __restrict__ out) {
    constexpr int C = D / 64;
    int lane = threadIdx.x & 63;
    int node = blockIdx.x * 4 + (threadIdx.x >> 6);
    if (node >= n) return;
    int beg = offs[node], end = offs[node + 1];
    float acc[C];
#pragma unroll
    for (int c = 0; c < C; c++) acc[c] = 0.f;
    for (int i = beg; i < end; i++) {
        int s = csr[i];  // wave-uniform
        const float* p = X + (size_t)s * D + lane * C;
        float f[C];
        if constexpr (C == 2) {
            float2 v = *reinterpret_cast<const float2*>(p);
            f[0] = v.x; f[1] = v.y;
        } else {
            float4 v = *reinterpret_cast<const float4*>(p);
            f[0] = v.x; f[1] = v.y; f[2] = v.z; f[3] = v.w;
        }
#pragma unroll
        for (int c = 0; c < C; c++)
            acc[c] = MAXAGG ? fmaxf(acc[c], f[c]) : (acc[c] + f[c]);
    }
    // mean: divide by max(deg,1); max: inputs are post-relu (>=0) so init 0 matches
    // both the running max and the empty-segment->0 rule.
    int d = end - beg; if (d < 1) d = 1;
    float scale = MAXAGG ? 1.f : (1.f / (float)d);
    uint16_t* q = out + (size_t)node * D + lane * C;
    uint16_t o[C];
#pragma unroll
    for (int c = 0; c < C; c++) o[c] = f2bfbits(acc[c] * scale);
    if constexpr (C == 2) {
        uint32_t v = o[0] | ((uint32_t)o[1] << 16);
        *reinterpret_cast<uint32_t*>(q) = v;
    } else {
        uint2 v;
        v.x = o[0] | ((uint32_t)o[1] << 16);
        v.y = o[2] | ((uint32_t)o[3] << 16);
        *reinterpret_cast<uint2*>(q) = v;
    }
}

// ---------------------- GEMM phase helper: acc += A[64x DIN-tile] @ W ----------------------
template<int DIN, int DOUT, typename TA>
DEV void gemm_accum(const TA* __restrict__ A, const float* __restrict__ W,
                    int row0, int col0, int n, int tid,
                    float (&as_t)[32][64], float (&ws_t)[32][64], float (&acc)[4][4]) {
    int tx = tid & 15, ty = tid >> 4;
    for (int kt = 0; kt < DIN; kt += 32) {
        {   // A tile: 64 rows x 32 k; each thread 8 contiguous elements
            int r = tid >> 2, k0 = (tid & 3) * 8;
            int row = row0 + r; if (row >= n) row = n - 1;
            float f[8];
            ld8(A + (size_t)row * DIN + kt + k0, f);
#pragma unroll
            for (int j = 0; j < 8; j++) as_t[k0 + j][r] = f[j];
        }
        {   // W tile: 32 k x 64 cols
            int k = tid >> 3, c0 = (tid & 7) * 8;
            float f[8];
            ld8(W + (size_t)(kt + k) * DOUT + col0 + c0, f);
#pragma unroll
            for (int j = 0; j < 8; j++) ws_t[k][c0 + j] = f[j];
        }
        __syncthreads();
#pragma unroll
        for (int k = 0; k < 32; k++) {
            float4 a = *reinterpret_cast<const float4*>(&as_t[k][ty * 4]);
            float4 w = *reinterpret_cast<const float4*>(&ws_t[k][tx * 4]);
            acc[0][0] += a.x * w.x; acc[0][1] += a.x * w.y; acc[0][2] += a.x * w.z; acc[0][3] += a.x * w.w;
            acc[1][0] += a.y * w.x; acc[1][1] += a.y * w.y; acc[1][2] += a.y * w.z; acc[1][3] += a.y * w.w;
            acc[2][0] += a.z * w.x; acc[2][1] += a.z * w.y; acc[2][2] += a.z * w.z; acc[2][3] += a.z * w.w;
            acc[3][0] += a.w * w.x; acc[3][1] += a.w * w.y; acc[3][2] += a.w * w.z; acc[3][3] += a.w * w.w;
        }
        __syncthreads();
    }
}

// ---------------------- fused (dual-)GEMM: out = A0@W0 (+ A1@W1) + bias ----------------------
// 64x64 tile, 256 threads, 4x4 per thread, fp32 accumulate, fp32 out
template<int DIN, int DOUT, bool DUAL, typename TA0, typename TA1>
__global__ __launch_bounds__(256) void k_gemm(const TA0* __restrict__ A0,
                                              const float* __restrict__ W0,
                                              const TA1* __restrict__ A1,
                                              const float* __restrict__ W1,
                                              const float* __restrict__ bias,
                                              int n, float* __restrict__ out) {
    __shared__ float as_t[32][64];  // [k][row]
    __shared__ float ws_t[32][64];  // [k][col]
    int tid = threadIdx.x;
    int tx = tid & 15, ty = tid >> 4;
    int row0 = blockIdx.x * 64, col0 = blockIdx.y * 64;
    float acc[4][4] = {};
    gemm_accum<DIN, DOUT>(A0, W0, row0, col0, n, tid, as_t, ws_t, acc);
    if constexpr (DUAL) {
        gemm_accum<DIN, DOUT>(A1, W1, row0, col0, n, tid, as_t, ws_t, acc);
    }
    float bj[4];
#pragma unroll
    for (int j = 0; j < 4; j++) bj[j] = bias[col0 + tx * 4 + j];
#pragma unroll
    for (int i = 0; i < 4; i++) {
        int row = row0 + ty * 4 + i;
        if (row < n) {
            float* q = out + (size_t)row * DOUT + col0 + tx * 4;
            float4 v;
            v.x = acc[i][0] + bj[0]; v.y = acc[i][1] + bj[1];
            v.z = acc[i][2] + bj[2]; v.w = acc[i][3] + bj[3];
            *reinterpret_cast<float4*>(q) = v;
        }
    }
}

// ---------------------- LayerNorm + ReLU, in place, one wave per row ----------------------
template<int D>
__global__ __launch_bounds__(256) void k_ln_relu(float* __restrict__ X,
                                                 const float* __restrict__ g,
                                                 const float* __restrict__ b, int n) {
    constexpr int C = D / 64;
    int lane = threadIdx.x & 63;
    int row = blockIdx.x * 4 + (threadIdx.x >> 6);
    if (row >= n) return;
    float* p = X + (size_t)row * D + lane * C;
    float f[C];
    if constexpr (C == 1) f[0] = p[0];
    else if constexpr (C == 2) { float2 v = *reinterpret_cast<const float2*>(p); f[0] = v.x; f[1] = v.y; }
    else { float4 v = *reinterpret_cast<const float4*>(p); f[0] = v.x; f[1] = v.y; f[2] = v.z; f[3] = v.w; }
    float s = 0.f, s2 = 0.f;
#pragma unroll
    for (int c = 0; c < C; c++) { s += f[c]; s2 += f[c] * f[c]; }
#pragma unroll
    for (int o = 32; o > 0; o >>= 1) { s += __shfl_xor(s, o); s2 += __shfl_xor(s2, o); }
    float mean = s / D;
    float var = s2 / D - mean * mean;
    float inv = rsqrtf(var + 1e-5f);
#pragma unroll
    for (int c = 0; c < C; c++) {
        float y = (f[c] - mean) * inv * g[lane * C + c] + b[lane * C + c];
        f[c] = fmaxf(y, 0.f);
    }
    if constexpr (C == 1) p[0] = f[0];
    else if constexpr (C == 2) { float2 v = {f[0], f[1]}; *reinterpret_cast<float2*>(p) = v; }
    else { float4 v = {f[0], f[1], f[2], f[3]}; *reinterpret_cast<float4*>(p) = v; }
}

// ---------------------- final projection: [N,64] @ [64,100] + b ----------------------
__global__ __launch_bounds__(128) void k_lo(const float* __restrict__ H,
                                            const float* __restrict__ W,
                                            const float* __restrict__ bias,
                                            int n, float* __restrict__ out) {
    __shared__ float row[64];
    int nr = blockIdx.x;
    int t = threadIdx.x;
    if (t < 32) {
        float2 v = *reinterpret_cast<const float2*>(H + (size_t)nr * 64 + t * 2);
        row[t * 2] = v.x; row[t * 2 + 1] = v.y;
    }
    __syncthreads();
    if (t < 100) {
        float acc = bias[t];
#pragma unroll
        for (int k = 0; k < 64; k++) acc += row[k] * W[k * 100 + t];
        out[(size_t)nr * 100 + t] = acc;
    }
}

// ---------------------- launcher ----------------------
extern "C" void kernel_launch(void* const* d_in, const int* in_sizes, int n_in,
                              void* d_out, int out_size, void* d_ws, size_t ws_size,
                              hipStream_t stream) {
    const float* x     = (const float*)d_in[0];
    const int*   src   = (const int*)d_in[1];
    const int*   dst   = (const int*)d_in[2];
    const float* s1_wl = (const float*)d_in[3];
    const float* s1_bl = (const float*)d_in[4];
    const float* s1_wr = (const float*)d_in[5];
    const float* ln1_g = (const float*)d_in[6];
    const float* ln1_b = (const float*)d_in[7];
    const float* s2_wl = (const float*)d_in[8];
    const float* s2_bl = (const float*)d_in[9];
    const float* s2_wr = (const float*)d_in[10];
    const float* ln2_g = (const float*)d_in[11];
    const float* ln2_b = (const float*)d_in[12];
    const float* s3_wl = (const float*)d_in[13];
    const float* s3_bl = (const float*)d_in[14];
    const float* s3_wr = (const float*)d_in[15];
    const float* ln3_g = (const float*)d_in[16];
    const float* ln3_b = (const float*)d_in[17];
    const float* l1_w  = (const float*)d_in[18];
    const float* l1_b  = (const float*)d_in[19];
    const float* ln4_g = (const float*)d_in[20];
    const float* ln4_b = (const float*)d_in[21];
    const float* lo_w  = (const float*)d_in[22];
    const float* lo_b  = (const float*)d_in[23];
    float* out = (float*)d_out;

    const int N = in_sizes[0] / 128;
    const int E = in_sizes[1];
    (void)n_in; (void)out_size; (void)ws_size;

    // workspace arena (~210 MB total)
    char* w = (char*)d_ws;
    size_t off = 0;
    auto alloc = [&](size_t bytes) -> void* {
        void* p = w + off;
        off = (off + bytes + 255) & ~(size_t)255;
        return p;
    };
    int* deg    = (int*)alloc((size_t)N * 4);
    int* offs   = (int*)alloc((size_t)(N + 1) * 4);
    int* cursor = (int*)alloc((size_t)N * 4);
    int* bsum   = (int*)alloc(1024 * 4);
    int* csr    = (int*)alloc((size_t)E * 4);
    uint16_t* aggrB = (uint16_t*)alloc((size_t)N * 256 * 2);  // bf16, all 3 aggr outputs
    float*    hA    = (float*)alloc((size_t)N * 128 * 4);     // h1 -> h3
    float*    hB    = (float*)alloc((size_t)N * 256 * 4);     // h2 -> h4

    int gE = (E + 255) / 256;
    int gN = (N + 255) / 256;
    int nb = (N + 1023) / 1024;
    int gNode = (N + 3) / 4;
    int gRow = (N + 63) / 64;

    // CSR build (reused by all three SAGE layers)
    hipMemsetAsync(deg, 0, (size_t)N * 4, stream);
    k_count<<<gE, 256, 0, stream>>>(dst, E, deg);
    k_block_sums<<<nb, 256, 0, stream>>>(deg, N, bsum);
    k_scan_bsums<<<1, 256, 0, stream>>>(bsum, nb);
    k_scan_final<<<nb, 256, 0, stream>>>(deg, N, bsum, offs);
    k_copy_int<<<gN, 256, 0, stream>>>(offs, cursor, N);
    k_scatter<<<gE, 256, 0, stream>>>(src, dst, E, cursor, csr);

    // layer 1: sage_mean(x) -> h1 [N,128]
    k_aggr<128, false><<<gNode, 256, 0, stream>>>(x, offs, csr, N, aggrB);
    k_gemm<128, 128, true, uint16_t, float><<<dim3(gRow, 2), 256, 0, stream>>>(
        aggrB, s1_wl, x, s1_wr, s1_bl, N, hA);
    k_ln_relu<128><<<gNode, 256, 0, stream>>>(hA, ln1_g, ln1_b, N);

    // layer 2: sage_max(h1) -> h2 [N,256]
    k_aggr<128, true><<<gNode, 256, 0, stream>>>(hA, offs, csr, N, aggrB);
    k_gemm<128, 256, true, uint16_t, float><<<dim3(gRow, 4), 256, 0, stream>>>(
        aggrB, s2_wl, hA, s2_wr, s2_bl, N, hB);
    k_ln_relu<256><<<gNode, 256, 0, stream>>>(hB, ln2_g, ln2_b, N);

    // layer 3: sage_mean(h2) -> h3 [N,128]
    k_aggr<256, false><<<gNode, 256, 0, stream>>>(hB, offs, csr, N, aggrB);
    k_gemm<256, 128, true, uint16_t, float><<<dim3(gRow, 2), 256, 0, stream>>>(
        aggrB, s3_wl, hB, s3_wr, s3_bl, N, hA);
    k_ln_relu<128><<<gNode, 256, 0, stream>>>(hA, ln3_g, ln3_b, N);

    // lin1: h3 @ l1_w + l1_b -> h4 [N,64]
    k_gemm<128, 64, false, float, float><<<dim3(gRow, 1), 256, 0, stream>>>(
        hA, l1_w, (const float*)nullptr, (const float*)nullptr, l1_b, N, hB);
    k_ln_relu<64><<<gNode, 256, 0, stream>>>(hB, ln4_g, ln4_b, N);

    // output: h4 @ lo_w + lo_b -> [N,100]
    k_lo<<<N, 128, 0, stream>>>(hB, lo_w, lo_b, N, out);
}

// Round 3
// 485.539 us; speedup vs baseline: 2.1560x; 2.1560x over previous
//
#include <hip/hip_runtime.h>
#include <stdint.h>

#define DEV __device__ __forceinline__

typedef __attribute__((ext_vector_type(8))) short bf16x8;   // 8 bf16 = 4 VGPRs
typedef __attribute__((ext_vector_type(4))) float f32x4;

// ---------- bf16 bit helpers ----------
DEV float bf2f(uint16_t u) { return __uint_as_float(((uint32_t)u) << 16); }
DEV uint16_t f2bfbits(float f) {          // round-to-nearest-even
    uint32_t x = __float_as_uint(f);
    uint32_t r = x + 0x7fffu + ((x >> 16) & 1u);
    return (uint16_t)(r >> 16);
}
DEV void stv(uint16_t* p, float v) { *p = f2bfbits(v); }
DEV void stv(float* p, float v) { *p = v; }

template<int C> DEV void ldbf(const uint16_t* p, float* f);
template<> DEV void ldbf<2>(const uint16_t* p, float* f) {
    uint32_t v = *reinterpret_cast<const uint32_t*>(p);
    f[0] = __uint_as_float(v << 16); f[1] = __uint_as_float(v & 0xffff0000u);
}
template<> DEV void ldbf<4>(const uint16_t* p, float* f) {
    uint2 v = *reinterpret_cast<const uint2*>(p);
    f[0] = __uint_as_float(v.x << 16); f[1] = __uint_as_float(v.x & 0xffff0000u);
    f[2] = __uint_as_float(v.y << 16); f[3] = __uint_as_float(v.y & 0xffff0000u);
}

// ---------------------- CSR build ----------------------
__global__ void k_count(const int* __restrict__ dst, int e, int* __restrict__ deg) {
    int i = blockIdx.x * 256 + threadIdx.x;
    if (i < e) atomicAdd(&deg[dst[i]], 1);
}

__global__ void k_block_sums(const int* __restrict__ deg, int n, int* __restrict__ bsum) {
    __shared__ int sm[256];
    int base = blockIdx.x * 1024;
    int s = 0;
    for (int i = threadIdx.x; i < 1024; i += 256) {
        int g = base + i;
        if (g < n) s += deg[g];
    }
    sm[threadIdx.x] = s; __syncthreads();
    for (int o = 128; o > 0; o >>= 1) {
        if (threadIdx.x < o) sm[threadIdx.x] += sm[threadIdx.x + o];
        __syncthreads();
    }
    if (threadIdx.x == 0) bsum[blockIdx.x] = sm[0];
}

__global__ void k_scan_bsums(int* bsum, int nb) {
    __shared__ int sm[256];
    int t = threadIdx.x;
    int v = (t < nb) ? bsum[t] : 0;
    sm[t] = v; __syncthreads();
    for (int o = 1; o < 256; o <<= 1) {
        int add = (t >= o) ? sm[t - o] : 0;
        __syncthreads();
        sm[t] += add;
        __syncthreads();
    }
    if (t < nb) bsum[t] = (t == 0) ? 0 : sm[t - 1];
}

__global__ void k_scan_final(const int* __restrict__ deg, int n,
                             const int* __restrict__ bsum, int* __restrict__ offs) {
    __shared__ int sm[256];
    int t = threadIdx.x;
    int i0 = blockIdx.x * 1024 + t * 4;
    int d0 = (i0     < n) ? deg[i0]     : 0;
    int d1 = (i0 + 1 < n) ? deg[i0 + 1] : 0;
    int d2 = (i0 + 2 < n) ? deg[i0 + 2] : 0;
    int d3 = (i0 + 3 < n) ? deg[i0 + 3] : 0;
    int ts = d0 + d1 + d2 + d3;
    sm[t] = ts; __syncthreads();
    for (int o = 1; o < 256; o <<= 1) {
        int add = (t >= o) ? sm[t - o] : 0;
        __syncthreads();
        sm[t] += add;
        __syncthreads();
    }
    int e0 = bsum[blockIdx.x] + ((t == 0) ? 0 : sm[t - 1]);
    int e1 = e0 + d0, e2 = e1 + d1, e3 = e2 + d2, e4 = e3 + d3;
    if (i0     < n) offs[i0]     = e0;
    if (i0 + 1 < n) offs[i0 + 1] = e1;
    if (i0 + 2 < n) offs[i0 + 2] = e2;
    if (i0 + 3 < n) offs[i0 + 3] = e3;
    if (i0 <= n - 1 && n - 1 < i0 + 4) offs[n] = e4;  // total
}

__global__ void k_copy_int(const int* __restrict__ a, int* __restrict__ b, int n) {
    int i = blockIdx.x * 256 + threadIdx.x;
    if (i < n) b[i] = a[i];
}

__global__ void k_scatter(const int* __restrict__ src, const int* __restrict__ dst, int e,
                          int* __restrict__ cursor, int* __restrict__ csr) {
    int i = blockIdx.x * 256 + threadIdx.x;
    if (i < e) {
        int p = atomicAdd(&cursor[dst[i]], 1);
        csr[p] = src[i];
    }
}

// ---------------------- fp32 -> bf16 convert ----------------------
__global__ void k_f2b(const float* __restrict__ in, uint16_t* __restrict__ o, int n4) {
    int i = blockIdx.x * 256 + threadIdx.x;
    if (i < n4) {
        float4 v = reinterpret_cast<const float4*>(in)[i];
        uint2 w;
        w.x = f2bfbits(v.x) | ((uint32_t)f2bfbits(v.y) << 16);
        w.y = f2bfbits(v.z) | ((uint32_t)f2bfbits(v.w) << 16);
        reinterpret_cast<uint2*>(o)[i] = w;
    }
}

// ---------------------- weight prep: transpose fp32 [K][Dreal] -> bf16 wt[n][koff+k], ldk ----------------------
__global__ void k_prep_wt(const float* __restrict__ W, uint16_t* __restrict__ wt,
                          int K, int Dreal, int Dpad, int koff, int ldk) {
    int idx = blockIdx.x * 256 + threadIdx.x;
    int total = Dpad * K;
    if (idx >= total) return;
    int nn = idx / K, k = idx - nn * K;
    float v = (nn < Dreal) ? W[(size_t)k * Dreal + nn] : 0.f;
    wt[(size_t)nn * ldk + koff + k] = f2bfbits(v);
}

// ---------------------- aggregation (bf16 in/out), mean or max ----------------------
template<int D, bool MAXAGG>
__global__ __launch_bounds__(256) void k_aggr(const uint16_t* __restrict__ X,
                                              const int* __restrict__ offs,
                                              const int* __restrict__ csr,
                                              int n, uint16_t* __restrict__ out) {
    constexpr int C = D / 64;                 // 2 or 4 bf16 per lane
    int lane = threadIdx.x & 63;
    int node = blockIdx.x * 4 + (threadIdx.x >> 6);
    if (node >= n) return;
    int beg = offs[node], end = offs[node + 1];
    float acc[C];
#pragma unroll
    for (int c = 0; c < C; c++) acc[c] = 0.f;
    const size_t loff = (size_t)lane * C;
    int i = beg;
    for (; i + 3 < end; i += 4) {             // 4 gathers in flight
        int s0 = csr[i], s1 = csr[i + 1], s2 = csr[i + 2], s3 = csr[i + 3];
        float f0[C], f1[C], f2[C], f3[C];
        ldbf<C>(X + (size_t)s0 * D + loff, f0);
        ldbf<C>(X + (size_t)s1 * D + loff, f1);
        ldbf<C>(X + (size_t)s2 * D + loff, f2);
        ldbf<C>(X + (size_t)s3 * D + loff, f3);
#pragma unroll
        for (int c = 0; c < C; c++) {
            if (MAXAGG) {
                acc[c] = fmaxf(acc[c], fmaxf(fmaxf(f0[c], f1[c]), fmaxf(f2[c], f3[c])));
            } else {
                acc[c] += (f0[c] + f1[c]) + (f2[c] + f3[c]);
            }
        }
    }
    for (; i < end; ++i) {
        int s = csr[i];
        float f[C];
        ldbf<C>(X + (size_t)s * D + loff, f);
#pragma unroll
        for (int c = 0; c < C; c++)
            acc[c] = MAXAGG ? fmaxf(acc[c], f[c]) : (acc[c] + f[c]);
    }
    int d = end - beg; if (d < 1) d = 1;
    float scale = MAXAGG ? 1.f : (1.f / (float)d);
    uint16_t* q = out + (size_t)node * D + loff;
    if constexpr (C == 2) {
        uint32_t v = f2bfbits(acc[0] * scale) | ((uint32_t)f2bfbits(acc[1] * scale) << 16);
        *reinterpret_cast<uint32_t*>(q) = v;
    } else {
        uint2 v;
        v.x = f2bfbits(acc[0] * scale) | ((uint32_t)f2bfbits(acc[1] * scale) << 16);
        v.y = f2bfbits(acc[2] * scale) | ((uint32_t)f2bfbits(acc[3] * scale) << 16);
        *reinterpret_cast<uint2*>(q) = v;
    }
}

// ---------------------- MFMA GEMM: out = [A0|A1] @ WT^T + bias, optional fused LN+ReLU ----------------------
// block = 128 rows x DPAD cols; 4 waves, wave owns 32 rows. WT is [DPAD][KEFF] bf16 (pre-transposed).
// A fragment: row=lane&15, k=(lane>>4)*8+j ; B fragment: col=lane&15, same k ; C/D: col=lane&15, row=(lane>>4)*4+reg.
template<int KPER, int DOUT, int DPAD, bool DUAL, bool LN, typename TO>
__global__ __launch_bounds__(256) void k_mf(const uint16_t* __restrict__ A0,
                                            const uint16_t* __restrict__ A1,
                                            const uint16_t* __restrict__ WT,
                                            const float* __restrict__ bias,
                                            const float* __restrict__ g,
                                            const float* __restrict__ bvec,
                                            int n, TO* __restrict__ out) {
    constexpr int KEFF = KPER * (DUAL ? 2 : 1);
    constexpr int NF = DPAD / 16;
    constexpr int APLANE = 128 * 16 + 16;   // bytes per k-chunk plane (+pad vs write conflicts)
    constexpr int WPLANE = DPAD * 16 + 16;
    __shared__ uint8_t aL[4 * APLANE];
    __shared__ uint8_t wL[4 * WPLANE];

    int tid = threadIdx.x;
    int lane = tid & 63, wid = tid >> 6;
    int lr = lane & 15, kb = lane >> 4;
    int row0 = blockIdx.x * 128;
    int wrow = wid * 32;

    f32x4 acc[2][NF] = {};

    for (int kt = 0; kt < KEFF; kt += 32) {
        const uint16_t* Asel = (DUAL && kt >= KPER) ? A1 : A0;
        int kk = (DUAL && kt >= KPER) ? kt - KPER : kt;
        __syncthreads();
        // stage A tile: 128 rows x 32 k = 512 x 16B chunks
#pragma unroll
        for (int it = 0; it < 2; ++it) {
            int c = tid + it * 256;
            int r = c >> 2, cb = c & 3;
            int row = row0 + r; if (row >= n) row = n - 1;
            uint4 v = *reinterpret_cast<const uint4*>(Asel + (size_t)row * KPER + kk + cb * 8);
            *reinterpret_cast<uint4*>(aL + cb * APLANE + r * 16) = v;
        }
        // stage W slice: DPAD rows x 32 k
        for (int c = tid; c < DPAD * 4; c += 256) {
            int nn = c >> 2, cb = c & 3;
            uint4 v = *reinterpret_cast<const uint4*>(WT + (size_t)nn * KEFF + kt + cb * 8);
            *reinterpret_cast<uint4*>(wL + cb * WPLANE + nn * 16) = v;
        }
        __syncthreads();
        bf16x8 af[2];
#pragma unroll
        for (int m = 0; m < 2; ++m)
            af[m] = *reinterpret_cast<const bf16x8*>(aL + kb * APLANE + (wrow + m * 16 + lr) * 16);
#pragma unroll
        for (int nf = 0; nf < NF; ++nf) {
            bf16x8 wf = *reinterpret_cast<const bf16x8*>(wL + kb * WPLANE + (nf * 16 + lr) * 16);
            acc[0][nf] = __builtin_amdgcn_mfma_f32_16x16x32_bf16(af[0], wf, acc[0][nf], 0, 0, 0);
            acc[1][nf] = __builtin_amdgcn_mfma_f32_16x16x32_bf16(af[1], wf, acc[1][nf], 0, 0, 0);
        }
    }

    // ---- epilogue: bias (+ LN + ReLU), store ----
    float bsv[NF];
#pragma unroll
    for (int nf = 0; nf < NF; ++nf) {
        int col = nf * 16 + lr;
        bsv[nf] = (DPAD == DOUT || col < DOUT) ? bias[col] : 0.f;
#pragma unroll
        for (int r = 0; r < 4; ++r) { acc[0][nf][r] += bsv[nf]; acc[1][nf][r] += bsv[nf]; }
    }
    if constexpr (LN) {
        float gv[NF], bv2[NF];
#pragma unroll
        for (int nf = 0; nf < NF; ++nf) {
            int col = nf * 16 + lr;
            gv[nf] = g[col]; bv2[nf] = bvec[col];
        }
#pragma unroll
        for (int m = 0; m < 2; ++m) {
            float s[4], s2[4];
#pragma unroll
            for (int r = 0; r < 4; ++r) { s[r] = 0.f; s2[r] = 0.f; }
#pragma unroll
            for (int nf = 0; nf < NF; ++nf)
#pragma unroll
                for (int r = 0; r < 4; ++r) { float v = acc[m][nf][r]; s[r] += v; s2[r] += v * v; }
#pragma unroll
            for (int r = 0; r < 4; ++r) {
#pragma unroll
                for (int o = 1; o < 16; o <<= 1) {   // xor within the 16-lane col group
                    s[r] += __shfl_xor(s[r], o);
                    s2[r] += __shfl_xor(s2[r], o);
                }
                float mean = s[r] / DOUT;
                float var = s2[r] / DOUT - mean * mean;
                float inv = rsqrtf(var + 1e-5f);
#pragma unroll
                for (int nf = 0; nf < NF; ++nf) {
                    float y = (acc[m][nf][r] - mean) * inv * gv[nf] + bv2[nf];
                    acc[m][nf][r] = fmaxf(y, 0.f);
                }
            }
        }
    }
#pragma unroll
    for (int m = 0; m < 2; ++m)
#pragma unroll
        for (int r = 0; r < 4; ++r) {
            int row = row0 + wrow + m * 16 + kb * 4 + r;
            if (row < n) {
#pragma unroll
                for (int nf = 0; nf < NF; ++nf) {
                    int col = nf * 16 + lr;
                    if (DPAD == DOUT || col < DOUT)
                        stv(out + (size_t)row * DOUT + col, acc[m][nf][r]);
                }
            }
        }
}

// ---------------------- launcher ----------------------
extern "C" void kernel_launch(void* const* d_in, const int* in_sizes, int n_in,
                              void* d_out, int out_size, void* d_ws, size_t ws_size,
                              hipStream_t stream) {
    const float* x     = (const float*)d_in[0];
    const int*   src   = (const int*)d_in[1];
    const int*   dst   = (const int*)d_in[2];
    const float* s1_wl = (const float*)d_in[3];
    const float* s1_bl = (const float*)d_in[4];
    const float* s1_wr = (const float*)d_in[5];
    const float* ln1_g = (const float*)d_in[6];
    const float* ln1_b = (const float*)d_in[7];
    const float* s2_wl = (const float*)d_in[8];
    const float* s2_bl = (const float*)d_in[9];
    const float* s2_wr = (const float*)d_in[10];
    const float* ln2_g = (const float*)d_in[11];
    const float* ln2_b = (const float*)d_in[12];
    const float* s3_wl = (const float*)d_in[13];
    const float* s3_bl = (const float*)d_in[14];
    const float* s3_wr = (const float*)d_in[15];
    const float* ln3_g = (const float*)d_in[16];
    const float* ln3_b = (const float*)d_in[17];
    const float* l1_w  = (const float*)d_in[18];
    const float* l1_b  = (const float*)d_in[19];
    const float* ln4_g = (const float*)d_in[20];
    const float* ln4_b = (const float*)d_in[21];
    const float* lo_w  = (const float*)d_in[22];
    const float* lo_b  = (const float*)d_in[23];
    float* out = (float*)d_out;

    const int N = in_sizes[0] / 128;
    const int E = in_sizes[1];
    (void)n_in; (void)out_size; (void)ws_size;

    char* w = (char*)d_ws;
    size_t off = 0;
    auto alloc = [&](size_t bytes) -> void* {
        void* p = w + off;
        off = (off + bytes + 255) & ~(size_t)255;
        return p;
    };
    int* deg    = (int*)alloc((size_t)N * 4);
    int* offs   = (int*)alloc((size_t)(N + 1) * 4);
    int* cursor = (int*)alloc((size_t)N * 4);
    int* bsum   = (int*)alloc(1024 * 4);
    int* csr    = (int*)alloc((size_t)E * 4);
    uint16_t* wt1 = (uint16_t*)alloc(128 * 256 * 2);   // [128][256]
    uint16_t* wt2 = (uint16_t*)alloc(256 * 256 * 2);   // [256][256]
    uint16_t* wt3 = (uint16_t*)alloc(128 * 512 * 2);   // [128][512]
    uint16_t* wt4 = (uint16_t*)alloc(64 * 128 * 2);    // [64][128]
    uint16_t* wt5 = (uint16_t*)alloc(112 * 64 * 2);    // [112][64] (zero-padded rows 100..111)
    uint16_t* xb    = (uint16_t*)alloc((size_t)N * 128 * 2);
    uint16_t* aggrB = (uint16_t*)alloc((size_t)N * 256 * 2);
    uint16_t* h1    = (uint16_t*)alloc((size_t)N * 128 * 2);
    uint16_t* h2    = (uint16_t*)alloc((size_t)N * 256 * 2);
    uint16_t* h3    = (uint16_t*)alloc((size_t)N * 128 * 2);
    uint16_t* h4    = (uint16_t*)alloc((size_t)N * 64 * 2);

    int gE = (E + 255) / 256;
    int gN = (N + 255) / 256;
    int nb = (N + 1023) / 1024;
    int gNode = (N + 3) / 4;
    int gMf = (N + 127) / 128;

    // CSR build
    hipMemsetAsync(deg, 0, (size_t)N * 4, stream);
    k_count<<<gE, 256, 0, stream>>>(dst, E, deg);
    k_block_sums<<<nb, 256, 0, stream>>>(deg, N, bsum);
    k_scan_bsums<<<1, 256, 0, stream>>>(bsum, nb);
    k_scan_final<<<nb, 256, 0, stream>>>(deg, N, bsum, offs);
    k_copy_int<<<gN, 256, 0, stream>>>(offs, cursor, N);
    k_scatter<<<gE, 256, 0, stream>>>(src, dst, E, cursor, csr);

    // weight prep (bf16 transposed, K-concat for dual layers)
    k_prep_wt<<<(128 * 128 + 255) / 256, 256, 0, stream>>>(s1_wl, wt1, 128, 128, 128, 0, 256);
    k_prep_wt<<<(128 * 128 + 255) / 256, 256, 0, stream>>>(s1_wr, wt1, 128, 128, 128, 128, 256);
    k_prep_wt<<<(256 * 128 + 255) / 256, 256, 0, stream>>>(s2_wl, wt2, 128, 256, 256, 0, 256);
    k_prep_wt<<<(256 * 128 + 255) / 256, 256, 0, stream>>>(s2_wr, wt2, 128, 256, 256, 128, 256);
    k_prep_wt<<<(128 * 256 + 255) / 256, 256, 0, stream>>>(s3_wl, wt3, 256, 128, 128, 0, 512);
    k_prep_wt<<<(128 * 256 + 255) / 256, 256, 0, stream>>>(s3_wr, wt3, 256, 128, 128, 256, 512);
    k_prep_wt<<<(64 * 128 + 255) / 256, 256, 0, stream>>>(l1_w, wt4, 128, 64, 64, 0, 128);
    k_prep_wt<<<(112 * 64 + 255) / 256, 256, 0, stream>>>(lo_w, wt5, 64, 100, 112, 0, 64);

    // x -> bf16
    k_f2b<<<(N * 128 / 4 + 255) / 256, 256, 0, stream>>>(x, xb, N * 128 / 4);

    // layer 1: mean-aggr + dual GEMM + LN/ReLU
    k_aggr<128, false><<<gNode, 256, 0, stream>>>(xb, offs, csr, N, aggrB);
    k_mf<128, 128, 128, true, true, uint16_t><<<gMf, 256, 0, stream>>>(
        aggrB, xb, wt1, s1_bl, ln1_g, ln1_b, N, h1);

    // layer 2: max-aggr + dual GEMM + LN/ReLU
    k_aggr<128, true><<<gNode, 256, 0, stream>>>(h1, offs, csr, N, aggrB);
    k_mf<128, 256, 256, true, true, uint16_t><<<gMf, 256, 0, stream>>>(
        aggrB, h1, wt2, s2_bl, ln2_g, ln2_b, N, h2);

    // layer 3: mean-aggr + dual GEMM + LN/ReLU
    k_aggr<256, false><<<gNode, 256, 0, stream>>>(h2, offs, csr, N, aggrB);
    k_mf<256, 128, 128, true, true, uint16_t><<<gMf, 256, 0, stream>>>(
        aggrB, h2, wt3, s3_bl, ln3_g, ln3_b, N, h3);

    // lin1 + LN/ReLU
    k_mf<128, 64, 64, false, true, uint16_t><<<gMf, 256, 0, stream>>>(
        h3, nullptr, wt4, l1_b, ln4_g, ln4_b, N, h4);

    // output projection (no LN), fp32 out
    k_mf<64, 100, 112, false, false, float><<<gMf, 256, 0, stream>>>(
        h4, nullptr, wt5, lo_b, nullptr, nullptr, N, out);
}

// Round 4
// 434.342 us; speedup vs baseline: 2.4101x; 1.1179x over previous
//
#include <hip/hip_runtime.h>
#include <stdint.h>

#define DEV __device__ __forceinline__

typedef __attribute__((ext_vector_type(8))) short bf16x8;   // 8 bf16 = 4 VGPRs
typedef __attribute__((ext_vector_type(4))) float f32x4;

// ---------- bf16 bit helpers ----------
DEV float bf2f(uint16_t u) { return __uint_as_float(((uint32_t)u) << 16); }
DEV uint16_t f2bfbits(float f) {          // round-to-nearest-even
    uint32_t x = __float_as_uint(f);
    uint32_t r = x + 0x7fffu + ((x >> 16) & 1u);
    return (uint16_t)(r >> 16);
}
DEV void stv(uint16_t* p, float v) { *p = f2bfbits(v); }
DEV void stv(float* p, float v) { *p = v; }

template<int C> DEV void ldbf(const uint16_t* p, float* f);
template<> DEV void ldbf<2>(const uint16_t* p, float* f) {
    uint32_t v = *reinterpret_cast<const uint32_t*>(p);
    f[0] = __uint_as_float(v << 16); f[1] = __uint_as_float(v & 0xffff0000u);
}
template<> DEV void ldbf<4>(const uint16_t* p, float* f) {
    uint2 v = *reinterpret_cast<const uint2*>(p);
    f[0] = __uint_as_float(v.x << 16); f[1] = __uint_as_float(v.x & 0xffff0000u);
    f[2] = __uint_as_float(v.y << 16); f[3] = __uint_as_float(v.y & 0xffff0000u);
}

// async global->LDS, 16B per lane; LDS dest = wave-uniform base + lane*16
DEV void gl16(const uint16_t* g, uint8_t* l) {
    __builtin_amdgcn_global_load_lds(
        (const __attribute__((address_space(1))) uint32_t*)g,
        (__attribute__((address_space(3))) uint32_t*)l, 16, 0, 0);
}

// ---------------------- CSR build ----------------------
__global__ void k_count(const int* __restrict__ dst, int e, int* __restrict__ deg) {
    int i = blockIdx.x * 256 + threadIdx.x;
    if (i < e) atomicAdd(&deg[dst[i]], 1);
}

__global__ void k_block_sums(const int* __restrict__ deg, int n, int* __restrict__ bsum) {
    __shared__ int sm[256];
    int base = blockIdx.x * 1024;
    int s = 0;
    for (int i = threadIdx.x; i < 1024; i += 256) {
        int g = base + i;
        if (g < n) s += deg[g];
    }
    sm[threadIdx.x] = s; __syncthreads();
    for (int o = 128; o > 0; o >>= 1) {
        if (threadIdx.x < o) sm[threadIdx.x] += sm[threadIdx.x + o];
        __syncthreads();
    }
    if (threadIdx.x == 0) bsum[blockIdx.x] = sm[0];
}

__global__ void k_scan_bsums(int* bsum, int nb) {
    __shared__ int sm[256];
    int t = threadIdx.x;
    int v = (t < nb) ? bsum[t] : 0;
    sm[t] = v; __syncthreads();
    for (int o = 1; o < 256; o <<= 1) {
        int add = (t >= o) ? sm[t - o] : 0;
        __syncthreads();
        sm[t] += add;
        __syncthreads();
    }
    if (t < nb) bsum[t] = (t == 0) ? 0 : sm[t - 1];
}

__global__ void k_scan_final(const int* __restrict__ deg, int n,
                             const int* __restrict__ bsum, int* __restrict__ offs,
                             int* __restrict__ cursor) {
    __shared__ int sm[256];
    int t = threadIdx.x;
    int i0 = blockIdx.x * 1024 + t * 4;
    int d0 = (i0     < n) ? deg[i0]     : 0;
    int d1 = (i0 + 1 < n) ? deg[i0 + 1] : 0;
    int d2 = (i0 + 2 < n) ? deg[i0 + 2] : 0;
    int d3 = (i0 + 3 < n) ? deg[i0 + 3] : 0;
    int ts = d0 + d1 + d2 + d3;
    sm[t] = ts; __syncthreads();
    for (int o = 1; o < 256; o <<= 1) {
        int add = (t >= o) ? sm[t - o] : 0;
        __syncthreads();
        sm[t] += add;
        __syncthreads();
    }
    int e0 = bsum[blockIdx.x] + ((t == 0) ? 0 : sm[t - 1]);
    int e1 = e0 + d0, e2 = e1 + d1, e3 = e2 + d2, e4 = e3 + d3;
    if (i0     < n) { offs[i0]     = e0; cursor[i0]     = e0; }
    if (i0 + 1 < n) { offs[i0 + 1] = e1; cursor[i0 + 1] = e1; }
    if (i0 + 2 < n) { offs[i0 + 2] = e2; cursor[i0 + 2] = e2; }
    if (i0 + 3 < n) { offs[i0 + 3] = e3; cursor[i0 + 3] = e3; }
    if (i0 <= n - 1 && n - 1 < i0 + 4) offs[n] = e4;  // total
}

__global__ void k_scatter(const int* __restrict__ src, const int* __restrict__ dst, int e,
                          int* __restrict__ cursor, int* __restrict__ csr) {
    int i = blockIdx.x * 256 + threadIdx.x;
    if (i < e) {
        int p = atomicAdd(&cursor[dst[i]], 1);
        csr[p] = src[i];
    }
}

// ---------------------- fp32 -> bf16 convert ----------------------
__global__ void k_f2b(const float* __restrict__ in, uint16_t* __restrict__ o, int n4) {
    int i = blockIdx.x * 256 + threadIdx.x;
    if (i < n4) {
        float4 v = reinterpret_cast<const float4*>(in)[i];
        uint2 w;
        w.x = f2bfbits(v.x) | ((uint32_t)f2bfbits(v.y) << 16);
        w.y = f2bfbits(v.z) | ((uint32_t)f2bfbits(v.w) << 16);
        reinterpret_cast<uint2*>(o)[i] = w;
    }
}

// ---------------------- fused weight prep: transpose fp32 [K][Dreal] -> bf16 wt[n][koff+k] ----------------------
struct PrepSeg { const float* W; uint16_t* wt; int K, Dreal, koff, ldk, start, end; };
struct PrepAll { PrepSeg s[8]; };

__global__ void k_prep_all(PrepAll P, int total) {
    int idx = blockIdx.x * 256 + threadIdx.x;
    if (idx >= total) return;
#pragma unroll
    for (int i = 0; i < 8; ++i) {
        if (idx >= P.s[i].start && idx < P.s[i].end) {
            int loc = idx - P.s[i].start;
            int K = P.s[i].K;
            int nn = loc / K, k = loc - nn * K;
            float v = (nn < P.s[i].Dreal) ? P.s[i].W[(size_t)k * P.s[i].Dreal + nn] : 0.f;
            P.s[i].wt[(size_t)nn * P.s[i].ldk + P.s[i].koff + k] = f2bfbits(v);
        }
    }
}

// ---------------------- aggregation (bf16 in/out), mean or max ----------------------
template<int D, bool MAXAGG>
__global__ __launch_bounds__(256) void k_aggr(const uint16_t* __restrict__ X,
                                              const int* __restrict__ offs,
                                              const int* __restrict__ csr,
                                              int n, uint16_t* __restrict__ out) {
    constexpr int C = D / 64;                 // 2 or 4 bf16 per lane
    int lane = threadIdx.x & 63;
    int node = blockIdx.x * 4 + (threadIdx.x >> 6);
    if (node >= n) return;
    int beg = offs[node], end = offs[node + 1];
    float acc[C];
#pragma unroll
    for (int c = 0; c < C; c++) acc[c] = 0.f;
    const size_t loff = (size_t)lane * C;
    int i = beg;
    for (; i + 3 < end; i += 4) {             // 4 gathers in flight
        int s0 = csr[i], s1 = csr[i + 1], s2 = csr[i + 2], s3 = csr[i + 3];
        float f0[C], f1[C], f2[C], f3[C];
        ldbf<C>(X + (size_t)s0 * D + loff, f0);
        ldbf<C>(X + (size_t)s1 * D + loff, f1);
        ldbf<C>(X + (size_t)s2 * D + loff, f2);
        ldbf<C>(X + (size_t)s3 * D + loff, f3);
#pragma unroll
        for (int c = 0; c < C; c++) {
            if (MAXAGG) {
                acc[c] = fmaxf(acc[c], fmaxf(fmaxf(f0[c], f1[c]), fmaxf(f2[c], f3[c])));
            } else {
                acc[c] += (f0[c] + f1[c]) + (f2[c] + f3[c]);
            }
        }
    }
    for (; i < end; ++i) {
        int s = csr[i];
        float f[C];
        ldbf<C>(X + (size_t)s * D + loff, f);
#pragma unroll
        for (int c = 0; c < C; c++)
            acc[c] = MAXAGG ? fmaxf(acc[c], f[c]) : (acc[c] + f[c]);
    }
    int d = end - beg; if (d < 1) d = 1;
    float scale = MAXAGG ? 1.f : (1.f / (float)d);
    uint16_t* q = out + (size_t)node * D + loff;
    if constexpr (C == 2) {
        uint32_t v = f2bfbits(acc[0] * scale) | ((uint32_t)f2bfbits(acc[1] * scale) << 16);
        *reinterpret_cast<uint32_t*>(q) = v;
    } else {
        uint2 v;
        v.x = f2bfbits(acc[0] * scale) | ((uint32_t)f2bfbits(acc[1] * scale) << 16);
        v.y = f2bfbits(acc[2] * scale) | ((uint32_t)f2bfbits(acc[3] * scale) << 16);
        *reinterpret_cast<uint2*>(q) = v;
    }
}

// ---------------------- MFMA GEMM: out = [A0|A1] @ WT^T + bias, optional fused LN+ReLU ----------------------
// block = 128 rows x DB cols; 4 waves, wave = 32 rows x DB cols.
// Staging via global_load_lds (16B/lane), double-buffered, one barrier per 32-k step.
// LDS layout (linear, lane-ordered): plane cb (8-k chunk) of 16B row/col chunks.
// A frag: row=lane&15, k=(lane>>4)*8+j ; B frag: col=lane&15 ; C/D: col=lane&15, row=(lane>>4)*4+reg.
template<int KPER, int DOUT, int DB, bool DUAL, bool LN, typename TO>
__global__ __launch_bounds__(256) void k_mf(const uint16_t* __restrict__ A0,
                                            const uint16_t* __restrict__ A1,
                                            const uint16_t* __restrict__ WT,
                                            const float* __restrict__ bias,
                                            const float* __restrict__ g,
                                            const float* __restrict__ bvec,
                                            int n, TO* __restrict__ out) {
    constexpr int KEFF = KPER * (DUAL ? 2 : 1);
    constexpr int NF = DB / 16;
    constexpr int WPL = DB * 16;          // W plane bytes per 8-k chunk
    constexpr int AB = 8192;              // A tile bytes (128 rows x 32 k x 2B)
    constexpr int WB = DB * 64;           // W tile bytes (DB cols x 32 k x 2B)
    constexpr int HB = DB / 64;           // W 1KB-chunks per plane (1,2,4)
    __shared__ __align__(16) uint8_t lds[2][AB + WB];

    int tid = threadIdx.x;
    int lane = tid & 63, wid = tid >> 6;
    int lr = lane & 15, kb = lane >> 4;
    int row0 = blockIdx.x * 128;
    int wrow = wid * 32;

    auto stage = [&](int kt, uint8_t* buf) {
        const uint16_t* Asel = A0; int kk = kt;
        if (DUAL && kt >= KPER) { Asel = A1; kk = kt - KPER; }
        uint8_t* aB = buf;
        uint8_t* wB = buf + AB;
        // A tile: 8 x 1KB chunks, 2 per wave. chunk p: plane cb=p>>1, row-half h=p&1
#pragma unroll
        for (int j = 0; j < 2; ++j) {
            int p = wid * 2 + j, cb = p >> 1, h = p & 1;
            int grow = row0 + h * 64 + lane; if (grow >= n) grow = n - 1;
            gl16(Asel + (size_t)grow * KPER + kk + cb * 8, aB + cb * 2048 + h * 1024);
        }
        // W tile: DB/16 x 1KB chunks, HB per wave. chunk p: cb=p/HB, col-half h=p%HB
#pragma unroll
        for (int j = 0; j < HB; ++j) {
            int p = wid * HB + j, cb = p / HB, h = p % HB;
            int c = h * 64 + lane;
            gl16(WT + (size_t)c * KEFF + kt + cb * 8, wB + cb * WPL + h * 1024);
        }
    };

    f32x4 acc[2][NF] = {};
    stage(0, lds[0]);
    __syncthreads();
    int cur = 0;
    for (int kt = 0; kt < KEFF; kt += 32) {
        if (kt + 32 < KEFF) stage(kt + 32, lds[cur ^ 1]);   // prefetch next tile
        const uint8_t* aB = lds[cur];
        const uint8_t* wB = lds[cur] + AB;
        bf16x8 af0 = *reinterpret_cast<const bf16x8*>(aB + kb * 2048 + (wrow + lr) * 16);
        bf16x8 af1 = *reinterpret_cast<const bf16x8*>(aB + kb * 2048 + (wrow + 16 + lr) * 16);
#pragma unroll
        for (int nf = 0; nf < NF; ++nf) {
            bf16x8 wf = *reinterpret_cast<const bf16x8*>(wB + kb * WPL + (nf * 16 + lr) * 16);
            acc[0][nf] = __builtin_amdgcn_mfma_f32_16x16x32_bf16(af0, wf, acc[0][nf], 0, 0, 0);
            acc[1][nf] = __builtin_amdgcn_mfma_f32_16x16x32_bf16(af1, wf, acc[1][nf], 0, 0, 0);
        }
        __syncthreads();   // drains prefetch (vmcnt 0) + frees lds[cur] for next prefetch
        cur ^= 1;
    }

    // ---- epilogue: bias (+ LN + ReLU), store ----
#pragma unroll
    for (int nf = 0; nf < NF; ++nf) {
        int col = nf * 16 + lr;
        float bsv = (DB == DOUT || col < DOUT) ? bias[col] : 0.f;
#pragma unroll
        for (int r = 0; r < 4; ++r) { acc[0][nf][r] += bsv; acc[1][nf][r] += bsv; }
    }
    if constexpr (LN) {
        float gv[NF], bv2[NF];
#pragma unroll
        for (int nf = 0; nf < NF; ++nf) {
            int col = nf * 16 + lr;
            gv[nf] = g[col]; bv2[nf] = bvec[col];
        }
#pragma unroll
        for (int m = 0; m < 2; ++m) {
            float s[4], s2[4];
#pragma unroll
            for (int r = 0; r < 4; ++r) { s[r] = 0.f; s2[r] = 0.f; }
#pragma unroll
            for (int nf = 0; nf < NF; ++nf)
#pragma unroll
                for (int r = 0; r < 4; ++r) { float v = acc[m][nf][r]; s[r] += v; s2[r] += v * v; }
#pragma unroll
            for (int r = 0; r < 4; ++r) {
#pragma unroll
                for (int o = 1; o < 16; o <<= 1) {   // xor within the 16-lane col group
                    s[r] += __shfl_xor(s[r], o);
                    s2[r] += __shfl_xor(s2[r], o);
                }
                float mean = s[r] / DOUT;
                float var = s2[r] / DOUT - mean * mean;
                float inv = rsqrtf(var + 1e-5f);
#pragma unroll
                for (int nf = 0; nf < NF; ++nf) {
                    float y = (acc[m][nf][r] - mean) * inv * gv[nf] + bv2[nf];
                    acc[m][nf][r] = fmaxf(y, 0.f);
                }
            }
        }
    }
#pragma unroll
    for (int m = 0; m < 2; ++m)
#pragma unroll
        for (int r = 0; r < 4; ++r) {
            int row = row0 + wrow + m * 16 + kb * 4 + r;
            if (row < n) {
#pragma unroll
                for (int nf = 0; nf < NF; ++nf) {
                    int col = nf * 16 + lr;
                    if (DB == DOUT || col < DOUT)
                        stv(out + (size_t)row * DOUT + col, acc[m][nf][r]);
                }
            }
        }
}

// ---------------------- launcher ----------------------
extern "C" void kernel_launch(void* const* d_in, const int* in_sizes, int n_in,
                              void* d_out, int out_size, void* d_ws, size_t ws_size,
                              hipStream_t stream) {
    const float* x     = (const float*)d_in[0];
    const int*   src   = (const int*)d_in[1];
    const int*   dst   = (const int*)d_in[2];
    const float* s1_wl = (const float*)d_in[3];
    const float* s1_bl = (const float*)d_in[4];
    const float* s1_wr = (const float*)d_in[5];
    const float* ln1_g = (const float*)d_in[6];
    const float* ln1_b = (const float*)d_in[7];
    const float* s2_wl = (const float*)d_in[8];
    const float* s2_bl = (const float*)d_in[9];
    const float* s2_wr = (const float*)d_in[10];
    const float* ln2_g = (const float*)d_in[11];
    const float* ln2_b = (const float*)d_in[12];
    const float* s3_wl = (const float*)d_in[13];
    const float* s3_bl = (const float*)d_in[14];
    const float* s3_wr = (const float*)d_in[15];
    const float* ln3_g = (const float*)d_in[16];
    const float* ln3_b = (const float*)d_in[17];
    const float* l1_w  = (const float*)d_in[18];
    const float* l1_b  = (const float*)d_in[19];
    const float* ln4_g = (const float*)d_in[20];
    const float* ln4_b = (const float*)d_in[21];
    const float* lo_w  = (const float*)d_in[22];
    const float* lo_b  = (const float*)d_in[23];
    float* out = (float*)d_out;

    const int N = in_sizes[0] / 128;
    const int E = in_sizes[1];
    (void)n_in; (void)out_size; (void)ws_size;

    char* w = (char*)d_ws;
    size_t off = 0;
    auto alloc = [&](size_t bytes) -> void* {
        void* p = w + off;
        off = (off + bytes + 255) & ~(size_t)255;
        return p;
    };
    int* deg    = (int*)alloc((size_t)N * 4);
    int* offs   = (int*)alloc((size_t)(N + 1) * 4);
    int* cursor = (int*)alloc((size_t)N * 4);
    int* bsum   = (int*)alloc(1024 * 4);
    int* csr    = (int*)alloc((size_t)E * 4);
    uint16_t* wt1 = (uint16_t*)alloc(128 * 256 * 2);   // [128][256]
    uint16_t* wt2 = (uint16_t*)alloc(256 * 256 * 2);   // [256][256]
    uint16_t* wt3 = (uint16_t*)alloc(128 * 512 * 2);   // [128][512]
    uint16_t* wt4 = (uint16_t*)alloc(64 * 128 * 2);    // [64][128]
    uint16_t* wt5 = (uint16_t*)alloc(128 * 64 * 2);    // [128][64] (cols 100..127 zero)
    uint16_t* xb    = (uint16_t*)alloc((size_t)N * 128 * 2);
    uint16_t* aggrB = (uint16_t*)alloc((size_t)N * 256 * 2);
    uint16_t* h1    = (uint16_t*)alloc((size_t)N * 128 * 2);
    uint16_t* h2    = (uint16_t*)alloc((size_t)N * 256 * 2);
    uint16_t* h3    = (uint16_t*)alloc((size_t)N * 128 * 2);
    uint16_t* h4    = (uint16_t*)alloc((size_t)N * 64 * 2);

    int gE = (E + 255) / 256;
    int nb = (N + 1023) / 1024;
    int gNode = (N + 3) / 4;
    int gMf = (N + 127) / 128;

    // CSR build
    hipMemsetAsync(deg, 0, (size_t)N * 4, stream);
    k_count<<<gE, 256, 0, stream>>>(dst, E, deg);
    k_block_sums<<<nb, 256, 0, stream>>>(deg, N, bsum);
    k_scan_bsums<<<1, 256, 0, stream>>>(bsum, nb);
    k_scan_final<<<nb, 256, 0, stream>>>(deg, N, bsum, offs, cursor);
    k_scatter<<<gE, 256, 0, stream>>>(src, dst, E, cursor, csr);

    // fused weight prep (bf16 transposed, K-concat for dual layers)
    PrepAll P;
    int cum = 0;
    auto seg = [&](int i, const float* W, uint16_t* wt, int K, int Dreal, int Dpad, int koff, int ldk) {
        P.s[i] = {W, wt, K, Dreal, koff, ldk, cum, cum + Dpad * K};
        cum += Dpad * K;
    };
    seg(0, s1_wl, wt1, 128, 128, 128, 0,   256);
    seg(1, s1_wr, wt1, 128, 128, 128, 128, 256);
    seg(2, s2_wl, wt2, 128, 256, 256, 0,   256);
    seg(3, s2_wr, wt2, 128, 256, 256, 128, 256);
    seg(4, s3_wl, wt3, 256, 128, 128, 0,   512);
    seg(5, s3_wr, wt3, 256, 128, 128, 256, 512);
    seg(6, l1_w,  wt4, 128, 64,  64,  0,   128);
    seg(7, lo_w,  wt5, 64,  100, 128, 0,   64);
    k_prep_all<<<(cum + 255) / 256, 256, 0, stream>>>(P, cum);

    // x -> bf16
    k_f2b<<<(N * 128 / 4 + 255) / 256, 256, 0, stream>>>(x, xb, N * 128 / 4);

    // layer 1: mean-aggr + dual GEMM + LN/ReLU
    k_aggr<128, false><<<gNode, 256, 0, stream>>>(xb, offs, csr, N, aggrB);
    k_mf<128, 128, 128, true, true, uint16_t><<<gMf, 256, 0, stream>>>(
        aggrB, xb, wt1, s1_bl, ln1_g, ln1_b, N, h1);

    // layer 2: max-aggr + dual GEMM + LN/ReLU
    k_aggr<128, true><<<gNode, 256, 0, stream>>>(h1, offs, csr, N, aggrB);
    k_mf<128, 256, 256, true, true, uint16_t><<<gMf, 256, 0, stream>>>(
        aggrB, h1, wt2, s2_bl, ln2_g, ln2_b, N, h2);

    // layer 3: mean-aggr + dual GEMM + LN/ReLU
    k_aggr<256, false><<<gNode, 256, 0, stream>>>(h2, offs, csr, N, aggrB);
    k_mf<256, 128, 128, true, true, uint16_t><<<gMf, 256, 0, stream>>>(
        aggrB, h2, wt3, s3_bl, ln3_g, ln3_b, N, h3);

    // lin1 + LN/ReLU
    k_mf<128, 64, 64, false, true, uint16_t><<<gMf, 256, 0, stream>>>(
        h3, nullptr, wt4, l1_b, ln4_g, ln4_b, N, h4);

    // output projection (no LN), fp32 out
    k_mf<64, 100, 128, false, false, float><<<gMf, 256, 0, stream>>>(
        h4, nullptr, wt5, lo_b, nullptr, nullptr, N, out);
}